// Round 2
// baseline (2787.742 us; speedup 1.0000x reference)
//
#include <hip/hip_runtime.h>

#define T_TOK 8192
#define H_DIM 2048
#define F_DIM 4096
#define NE 8
#define NSLOT (T_TOK * 2)
#define BK 64

using bf16x8 = __attribute__((ext_vector_type(8))) __bf16;
using f32x4  = __attribute__((ext_vector_type(4))) float;
using u16x4  = __attribute__((ext_vector_type(4))) unsigned short;

__device__ __forceinline__ unsigned short f2bf(float f) {
  unsigned int u = __float_as_uint(f);
  unsigned int r = (u + 0x7FFFu + ((u >> 16) & 1u)) >> 16;  // RNE; inputs finite
  return (unsigned short)r;
}

__device__ __forceinline__ void gload_lds16(const void* g, void* l) {
  __builtin_amdgcn_global_load_lds(
      (const __attribute__((address_space(1))) void*)g,
      (__attribute__((address_space(3))) void*)l, 16, 0, 0);
}

// ---------------- tiny kernels ----------------
__global__ void k_zero(int* counts) {
  if (threadIdx.x < NE) counts[threadIdx.x] = 0;
}

__global__ void k_cast_x(const float* __restrict__ x, unsigned short* __restrict__ xbf) {
  const int n4 = T_TOK * H_DIM / 4;
  for (int i = blockIdx.x * 256 + threadIdx.x; i < n4; i += gridDim.x * 256) {
    f32x4 v = ((const f32x4*)x)[i];
    u16x4 o;
    o[0] = f2bf(v[0]); o[1] = f2bf(v[1]); o[2] = f2bf(v[2]); o[3] = f2bf(v[3]);
    ((u16x4*)xbf)[i] = o;
  }
}

// one wave per token: 8 logits, top-2, renormalized weights
__global__ __launch_bounds__(256) void k_router(
    const float* __restrict__ x, const float* __restrict__ gw,
    int* __restrict__ counts, int* __restrict__ eids, float* __restrict__ wts) {
  const int wave = threadIdx.x >> 6, lane = threadIdx.x & 63;
  const int tok = blockIdx.x * 4 + wave;
  const float* xr = x + (size_t)tok * H_DIM;
  float acc[NE];
  #pragma unroll
  for (int e = 0; e < NE; ++e) acc[e] = 0.f;
  for (int j = 0; j < H_DIM / 64; ++j) {
    int i = j * 64 + lane;
    float xv = xr[i];
    #pragma unroll
    for (int e = 0; e < NE; ++e) acc[e] += xv * gw[e * H_DIM + i];
  }
  #pragma unroll
  for (int e = 0; e < NE; ++e) {
    float v = acc[e];
    #pragma unroll
    for (int o = 32; o >= 1; o >>= 1) v += __shfl_xor(v, o);
    acc[e] = v;
  }
  int e0 = 0; float l0 = acc[0];
  #pragma unroll
  for (int e = 1; e < NE; ++e) if (acc[e] > l0) { l0 = acc[e]; e0 = e; }
  int e1 = -1; float l1 = -3.4e38f;
  #pragma unroll
  for (int e = 0; e < NE; ++e) if (e != e0 && acc[e] > l1) { l1 = acc[e]; e1 = e; }
  if (lane == 0) {
    float w0 = 1.f / (1.f + expf(l1 - l0));   // == p0/(p0+p1)
    eids[2 * tok] = e0; eids[2 * tok + 1] = e1;
    wts[2 * tok] = w0;  wts[2 * tok + 1] = 1.f - w0;
    atomicAdd(&counts[e0], 1); atomicAdd(&counts[e1], 1);
  }
}

__global__ void k_prefix(const int* __restrict__ counts, int* __restrict__ offsets,
                         int* __restrict__ cursors) {
  if (threadIdx.x == 0) {
    int s = 0;
    for (int e = 0; e < NE; ++e) { offsets[e] = s; cursors[e] = s; s += counts[e]; }
    offsets[NE] = s;
  }
}

__global__ void k_scatter(const int* __restrict__ eids, const float* __restrict__ wts,
                          int* __restrict__ cursors, int* __restrict__ token_list,
                          float* __restrict__ slot_w, int* __restrict__ slot_of) {
  int t = blockIdx.x * 256 + threadIdx.x;
  if (t >= T_TOK) return;
  #pragma unroll
  for (int k = 0; k < 2; ++k) {
    int e = eids[2 * t + k];
    int pos = atomicAdd(&cursors[e], 1);
    token_list[pos] = t;
    slot_w[pos] = wts[2 * t + k];
    slot_of[2 * t + k] = pos;
  }
}

// ---------------- grouped GEMM1: h = silu(x w1^T) * (x w3^T) ----------------
// tile 128M x 128N(F), BK=64, 4 waves 2x2, dual-B, bf16 MFMA 16x16x32
__global__ __launch_bounds__(256) void k_gemm1(
    const unsigned short* __restrict__ xbf,
    const float* __restrict__ w1, const float* __restrict__ w3,
    const int* __restrict__ offsets, const int* __restrict__ token_list,
    unsigned short* __restrict__ hbuf)
{
  const int e   = blockIdx.z;
  const int off = offsets[e];
  const int n_e = offsets[e + 1] - off;
  const int m0  = blockIdx.y * 128;
  if (m0 >= n_e) return;
  const int n0  = blockIdx.x * 128;

  __shared__ alignas(16) char lds[16384 + 32768];  // A(16K) | B1(16K) | B3(16K)
  char* ldsA = lds;
  char* ldsB = lds + 16384;

  const int t = threadIdx.x, lane = t & 63, wave = t >> 6;

  // A staging: linear LDS dest; source pre-swizzled (rule 21). Row = j*32 + t/8, slot = t&7.
  const unsigned short* aSrc[4];
  #pragma unroll
  for (int j = 0; j < 4; ++j) {
    int row = j * 32 + (t >> 3);
    int sl  = (t & 7) ^ (row & 7);
    int mg  = m0 + row;
    int tok = (mg < n_e) ? token_list[off + mg] : 0;
    aSrc[j] = xbf + (size_t)tok * H_DIM + sl * 8;
  }
  // B staging (reg-staged fp32->bf16): chunk i: n=i*16+(t>>4), c=t&15
  const int c    = t & 15;
  const int nsub = t >> 4;
  const int bbase = nsub * 128 + (((c >> 1) ^ (nsub & 7)) << 4) + (c & 1) * 8;
  const int wboff = (n0 + nsub) * H_DIM + c * 4;
  const float* w1e = w1 + (size_t)e * F_DIM * H_DIM;
  const float* w3e = w3 + (size_t)e * F_DIM * H_DIM;

  const int lo = lane & 15, hi = lane >> 4;
  const int wm = (wave >> 1) * 64, wn = (wave & 1) * 64;
  const int rbaseA = (wm + lo) * 128;
  const int rbaseB = (wn + lo) * 128;
  const int x0 = ((hi    ) ^ (lo & 7)) << 4;
  const int x1 = ((hi + 4) ^ (lo & 7)) << 4;

  f32x4 accg[4][4], accu[4][4];
  const f32x4 zero = {0.f, 0.f, 0.f, 0.f};
  #pragma unroll
  for (int m = 0; m < 4; ++m)
    #pragma unroll
    for (int n = 0; n < 4; ++n) { accg[m][n] = zero; accu[m][n] = zero; }

  for (int k0 = 0; k0 < H_DIM; k0 += BK) {
    #pragma unroll
    for (int j = 0; j < 4; ++j)
      gload_lds16(aSrc[j] + k0, ldsA + j * 4096 + wave * 1024);
    // w1 panel, then w3 panel (split loops: halve staging register pressure)
    #pragma unroll
    for (int i = 0; i < 8; ++i) {
      f32x4 v = *(const f32x4*)(w1e + wboff + i * (16 * H_DIM) + k0);
      u16x4 o;
      o[0] = f2bf(v[0]); o[1] = f2bf(v[1]); o[2] = f2bf(v[2]); o[3] = f2bf(v[3]);
      *(u16x4*)(ldsB + i * 2048 + bbase) = o;
    }
    #pragma unroll
    for (int i = 0; i < 8; ++i) {
      f32x4 v = *(const f32x4*)(w3e + wboff + i * (16 * H_DIM) + k0);
      u16x4 o;
      o[0] = f2bf(v[0]); o[1] = f2bf(v[1]); o[2] = f2bf(v[2]); o[3] = f2bf(v[3]);
      *(u16x4*)(ldsB + 16384 + i * 2048 + bbase) = o;
    }
    __syncthreads();
    #pragma unroll
    for (int kk = 0; kk < 2; ++kk) {
      const int xk = kk ? x1 : x0;
      bf16x8 af[4];
      #pragma unroll
      for (int m = 0; m < 4; ++m)
        af[m] = *(const bf16x8*)(ldsA + rbaseA + m * 2048 + xk);
      #pragma unroll
      for (int n = 0; n < 4; ++n) {
        bf16x8 b1 = *(const bf16x8*)(ldsB +         rbaseB + n * 2048 + xk);
        bf16x8 b3 = *(const bf16x8*)(ldsB + 16384 + rbaseB + n * 2048 + xk);
        #pragma unroll
        for (int m = 0; m < 4; ++m) {
          accg[m][n] = __builtin_amdgcn_mfma_f32_16x16x32_bf16(af[m], b1, accg[m][n], 0, 0, 0);
          accu[m][n] = __builtin_amdgcn_mfma_f32_16x16x32_bf16(af[m], b3, accu[m][n], 0, 0, 0);
        }
      }
    }
    __syncthreads();
  }
  // epilogue: D row=(lane>>4)*4+r, col=lane&15 (m89/m91 layout)
  #pragma unroll
  for (int m = 0; m < 4; ++m) {
    #pragma unroll
    for (int r = 0; r < 4; ++r) {
      int mg = m0 + wm + m * 16 + hi * 4 + r;
      if (mg < n_e) {
        unsigned short* dst = hbuf + (size_t)(off + mg) * F_DIM + n0 + wn + lo;
        #pragma unroll
        for (int n = 0; n < 4; ++n) {
          float g = accg[m][n][r];
          float u = accu[m][n][r];
          float h = (g / (1.f + expf(-g))) * u;
          dst[n * 16] = f2bf(h);
        }
      }
    }
  }
}

// ---------------- grouped GEMM2: part[slot] = (h w2^T) * slot_w ----------------
__global__ __launch_bounds__(256) void k_gemm2(
    const unsigned short* __restrict__ hbuf, const float* __restrict__ w2,
    const int* __restrict__ offsets, const float* __restrict__ slot_w,
    float* __restrict__ part)
{
  const int e   = blockIdx.z;
  const int off = offsets[e];
  const int n_e = offsets[e + 1] - off;
  const int m0  = blockIdx.y * 128;
  if (m0 >= n_e) return;
  const int n0  = blockIdx.x * 128;

  __shared__ alignas(16) char lds[32768];  // A(16K) | B(16K)
  char* ldsA = lds;
  char* ldsB = lds + 16384;

  const int t = threadIdx.x, lane = t & 63, wave = t >> 6;

  const unsigned short* aSrc[4];
  #pragma unroll
  for (int j = 0; j < 4; ++j) {
    int row = j * 32 + (t >> 3);
    int sl  = (t & 7) ^ (row & 7);
    int mg  = m0 + row; if (mg >= n_e) mg = n_e - 1;   // clamp: stay in valid hbuf rows
    aSrc[j] = hbuf + (size_t)(off + mg) * F_DIM + sl * 8;
  }
  const int c    = t & 15;
  const int nsub = t >> 4;
  const int bbase = nsub * 128 + (((c >> 1) ^ (nsub & 7)) << 4) + (c & 1) * 8;
  const int wboff = (n0 + nsub) * F_DIM + c * 4;
  const float* w2e = w2 + (size_t)e * H_DIM * F_DIM;

  const int lo = lane & 15, hi = lane >> 4;
  const int wm = (wave >> 1) * 64, wn = (wave & 1) * 64;
  const int rbaseA = (wm + lo) * 128;
  const int rbaseB = (wn + lo) * 128;
  const int x0 = ((hi    ) ^ (lo & 7)) << 4;
  const int x1 = ((hi + 4) ^ (lo & 7)) << 4;

  f32x4 acc[4][4];
  const f32x4 zero = {0.f, 0.f, 0.f, 0.f};
  #pragma unroll
  for (int m = 0; m < 4; ++m)
    #pragma unroll
    for (int n = 0; n < 4; ++n) acc[m][n] = zero;

  for (int k0 = 0; k0 < F_DIM; k0 += BK) {
    #pragma unroll
    for (int j = 0; j < 4; ++j)
      gload_lds16(aSrc[j] + k0, ldsA + j * 4096 + wave * 1024);
    #pragma unroll
    for (int i = 0; i < 8; ++i) {
      f32x4 v = *(const f32x4*)(w2e + wboff + i * (16 * F_DIM) + k0);
      u16x4 o;
      o[0] = f2bf(v[0]); o[1] = f2bf(v[1]); o[2] = f2bf(v[2]); o[3] = f2bf(v[3]);
      *(u16x4*)(ldsB + i * 2048 + bbase) = o;
    }
    __syncthreads();
    #pragma unroll
    for (int kk = 0; kk < 2; ++kk) {
      const int xk = kk ? x1 : x0;
      bf16x8 af[4], bfr[4];
      #pragma unroll
      for (int m = 0; m < 4; ++m) af[m]  = *(const bf16x8*)(ldsA + rbaseA + m * 2048 + xk);
      #pragma unroll
      for (int n = 0; n < 4; ++n) bfr[n] = *(const bf16x8*)(ldsB + rbaseB + n * 2048 + xk);
      #pragma unroll
      for (int m = 0; m < 4; ++m)
        #pragma unroll
        for (int n = 0; n < 4; ++n)
          acc[m][n] = __builtin_amdgcn_mfma_f32_16x16x32_bf16(af[m], bfr[n], acc[m][n], 0, 0, 0);
    }
    __syncthreads();
  }
  #pragma unroll
  for (int m = 0; m < 4; ++m) {
    #pragma unroll
    for (int r = 0; r < 4; ++r) {
      int mg = m0 + wm + m * 16 + hi * 4 + r;
      if (mg < n_e) {
        int slot = off + mg;
        float sw = slot_w[slot];
        float* dst = part + (size_t)slot * H_DIM + n0 + wn + lo;
        #pragma unroll
        for (int n = 0; n < 4; ++n) dst[n * 16] = acc[m][n][r] * sw;
      }
    }
  }
}

// ---------------- combine: out[t] = part[slot0(t)] + part[slot1(t)] ----------------
__global__ __launch_bounds__(256) void k_combine(
    const float* __restrict__ part, const int* __restrict__ slot_of,
    float* __restrict__ out) {
  int tok = blockIdx.x;
  int s0 = slot_of[2 * tok], s1 = slot_of[2 * tok + 1];
  const f32x4* p0 = (const f32x4*)(part + (size_t)s0 * H_DIM);
  const f32x4* p1 = (const f32x4*)(part + (size_t)s1 * H_DIM);
  f32x4* o = (f32x4*)(out + (size_t)tok * H_DIM);
  for (int i = threadIdx.x; i < H_DIM / 4; i += 256) o[i] = p0[i] + p1[i];
}

// ---------------- launch ----------------
extern "C" void kernel_launch(void* const* d_in, const int* in_sizes, int n_in,
                              void* d_out, int out_size, void* d_ws, size_t ws_size,
                              hipStream_t stream) {
  (void)in_sizes; (void)n_in; (void)out_size; (void)ws_size;
  const float* x  = (const float*)d_in[0];
  const float* gw = (const float*)d_in[1];
  const float* w1 = (const float*)d_in[2];
  const float* w3 = (const float*)d_in[3];
  const float* w2 = (const float*)d_in[4];
  float* out = (float*)d_out;

  char* ws = (char*)d_ws;
  size_t p = 0;
  auto alloc = [&](size_t bytes) -> char* {
    char* r = ws + p;
    p = (p + bytes + 255) & ~(size_t)255;
    return r;
  };
  int*   counts     = (int*)alloc(NE * 4);
  int*   cursors    = (int*)alloc(NE * 4);
  int*   offsets    = (int*)alloc((NE + 1) * 4);
  int*   eids       = (int*)alloc((size_t)NSLOT * 4);
  float* wts        = (float*)alloc((size_t)NSLOT * 4);
  int*   token_list = (int*)alloc((size_t)NSLOT * 4);
  float* slot_w     = (float*)alloc((size_t)NSLOT * 4);
  int*   slot_of    = (int*)alloc((size_t)NSLOT * 4);
  unsigned short* xbf  = (unsigned short*)alloc((size_t)T_TOK * H_DIM * 2);
  unsigned short* hbuf = (unsigned short*)alloc((size_t)NSLOT * F_DIM * 2);
  float*          part = (float*)alloc((size_t)NSLOT * H_DIM * 4);
  // total ws use ≈ 302 MB

  k_zero<<<dim3(1), dim3(64), 0, stream>>>(counts);
  k_cast_x<<<dim3(4096), dim3(256), 0, stream>>>(x, xbf);
  k_router<<<dim3(T_TOK / 4), dim3(256), 0, stream>>>(x, gw, counts, eids, wts);
  k_prefix<<<dim3(1), dim3(1), 0, stream>>>(counts, offsets, cursors);
  k_scatter<<<dim3(T_TOK / 256), dim3(256), 0, stream>>>(eids, wts, cursors, token_list,
                                                         slot_w, slot_of);
  // worst case 8192 rows/expert -> 64 M-tiles; inactive tiles exit on offsets read
  k_gemm1<<<dim3(F_DIM / 128, 64, NE), dim3(256), 0, stream>>>(xbf, w1, w3, offsets,
                                                               token_list, hbuf);
  k_gemm2<<<dim3(H_DIM / 128, 64, NE), dim3(256), 0, stream>>>(hbuf, w2, offsets,
                                                               slot_w, part);
  k_combine<<<dim3(T_TOK), dim3(256), 0, stream>>>(part, slot_of, out);
}

// Round 6
// 2741.797 us; speedup vs baseline: 1.0168x; 1.0168x over previous
//
#include <hip/hip_runtime.h>

#define T_TOK 8192
#define H_DIM 2048
#define F_DIM 4096
#define NE 8
#define NSLOT (T_TOK * 2)
#define BK 64
#define FH (F_DIM * H_DIM)          // 8388608 = 2^23
#define EPERPH 4                    // experts staged per phase

using bf16x8 = __attribute__((ext_vector_type(8))) __bf16;
using f32x4  = __attribute__((ext_vector_type(4))) float;
using u16x4  = __attribute__((ext_vector_type(4))) unsigned short;

__device__ __forceinline__ unsigned short f2bf(float f) {
  unsigned int u = __float_as_uint(f);
  unsigned int r = (u + 0x7FFFu + ((u >> 16) & 1u)) >> 16;  // RNE; inputs finite
  return (unsigned short)r;
}

__device__ __forceinline__ void gload_lds16(const void* g, void* l) {
  __builtin_amdgcn_global_load_lds(
      (const __attribute__((address_space(1))) void*)g,
      (__attribute__((address_space(3))) void*)l, 16, 0, 0);
}

// ---------------- tiny kernels ----------------
__global__ void k_zero(int* counts) {
  if (threadIdx.x < NE) counts[threadIdx.x] = 0;
}

__global__ __launch_bounds__(256) void k_zero_out(float* __restrict__ out, int n4) {
  const f32x4 z = {0.f, 0.f, 0.f, 0.f};
  for (int i = blockIdx.x * 256 + threadIdx.x; i < n4; i += gridDim.x * 256)
    ((f32x4*)out)[i] = z;
}

// fp32 -> bf16 cast, grid-stride over f32x4 chunks (contiguous src/dst)
__global__ __launch_bounds__(256) void k_cast(const float* __restrict__ src,
                                              unsigned short* __restrict__ dst, int n4) {
  for (int i = blockIdx.x * 256 + threadIdx.x; i < n4; i += gridDim.x * 256) {
    f32x4 v = ((const f32x4*)src)[i];
    u16x4 o;
    o[0] = f2bf(v[0]); o[1] = f2bf(v[1]); o[2] = f2bf(v[2]); o[3] = f2bf(v[3]);
    ((u16x4*)dst)[i] = o;
  }
}

// cast w1/w3 for EPERPH experts into wstage layout [el][mat][F][H] (bf16)
// i indexes f32x4 chunks of the phase: el=i>>22, mat=(i>>21)&1, off4=i&0x1FFFFF
__global__ __launch_bounds__(256) void k_cast_w13(
    const float* __restrict__ w1, const float* __restrict__ w3,
    unsigned short* __restrict__ dst, int e_base) {
  const int n4 = EPERPH * 2 * FH / 4;  // 2^24
  for (int i = blockIdx.x * 256 + threadIdx.x; i < n4; i += gridDim.x * 256) {
    int el   = i >> 22;
    int mat  = (i >> 21) & 1;
    int off4 = i & 0x1FFFFF;
    const float* src = (mat ? w3 : w1) + ((size_t)(e_base + el) << 23);
    f32x4 v = ((const f32x4*)src)[off4];
    u16x4 o;
    o[0] = f2bf(v[0]); o[1] = f2bf(v[1]); o[2] = f2bf(v[2]); o[3] = f2bf(v[3]);
    ((u16x4*)dst)[i] = o;
  }
}

// one wave per token: 8 logits, top-2, renormalized weights
__global__ __launch_bounds__(256) void k_router(
    const float* __restrict__ x, const float* __restrict__ gw,
    int* __restrict__ counts, int* __restrict__ eids, float* __restrict__ wts) {
  const int wave = threadIdx.x >> 6, lane = threadIdx.x & 63;
  const int tok = blockIdx.x * 4 + wave;
  const float* xr = x + (size_t)tok * H_DIM;
  float acc[NE];
  #pragma unroll
  for (int e = 0; e < NE; ++e) acc[e] = 0.f;
  for (int j = 0; j < H_DIM / 64; ++j) {
    int i = j * 64 + lane;
    float xv = xr[i];
    #pragma unroll
    for (int e = 0; e < NE; ++e) acc[e] += xv * gw[e * H_DIM + i];
  }
  #pragma unroll
  for (int e = 0; e < NE; ++e) {
    float v = acc[e];
    #pragma unroll
    for (int o = 32; o >= 1; o >>= 1) v += __shfl_xor(v, o);
    acc[e] = v;
  }
  int e0 = 0; float l0 = acc[0];
  #pragma unroll
  for (int e = 1; e < NE; ++e) if (acc[e] > l0) { l0 = acc[e]; e0 = e; }
  int e1 = -1; float l1 = -3.4e38f;
  #pragma unroll
  for (int e = 0; e < NE; ++e) if (e != e0 && acc[e] > l1) { l1 = acc[e]; e1 = e; }
  if (lane == 0) {
    float w0 = 1.f / (1.f + expf(l1 - l0));   // == p0/(p0+p1)
    eids[2 * tok] = e0; eids[2 * tok + 1] = e1;
    wts[2 * tok] = w0;  wts[2 * tok + 1] = 1.f - w0;
    atomicAdd(&counts[e0], 1); atomicAdd(&counts[e1], 1);
  }
}

__global__ void k_prefix(const int* __restrict__ counts, int* __restrict__ offsets,
                         int* __restrict__ cursors) {
  if (threadIdx.x == 0) {
    int s = 0;
    for (int e = 0; e < NE; ++e) { offsets[e] = s; cursors[e] = s; s += counts[e]; }
    offsets[NE] = s;
  }
}

__global__ void k_scatter(const int* __restrict__ eids, const float* __restrict__ wts,
                          int* __restrict__ cursors, int* __restrict__ token_list,
                          float* __restrict__ slot_w) {
  int t = blockIdx.x * 256 + threadIdx.x;
  if (t >= T_TOK) return;
  #pragma unroll
  for (int k = 0; k < 2; ++k) {
    int e = eids[2 * t + k];
    int pos = atomicAdd(&cursors[e], 1);
    token_list[pos] = t;
    slot_w[pos] = wts[2 * t + k];
  }
}

// ---------------- grouped GEMM1: h = silu(x w1^T) * (x w3^T) ----------------
// tile 128M x 128N(F), BK=64, 4 waves 2x2, dual-B, bf16 MFMA 16x16x32
// A and both B panels staged via global_load_lds w16 (linear dest, pre-swizzled src)
// weights come from wstage [el][mat][F][H] bf16 for experts e_base..e_base+3
__global__ __launch_bounds__(256) void k_gemm1(
    const unsigned short* __restrict__ xbf,
    const unsigned short* __restrict__ wstage,
    const int* __restrict__ offsets, const int* __restrict__ token_list,
    unsigned short* __restrict__ hbuf, int e_base)
{
  const int el  = blockIdx.z;
  const int e   = e_base + el;
  const int off = offsets[e];
  const int n_e = offsets[e + 1] - off;
  const int m0  = blockIdx.y * 128;
  if (m0 >= n_e) return;
  const int n0  = blockIdx.x * 128;

  __shared__ alignas(16) char lds[49152];  // A(16K) | B1(16K) | B3(16K)
  char* ldsA  = lds;
  char* ldsB1 = lds + 16384;
  char* ldsB3 = lds + 32768;

  const int t = threadIdx.x, lane = t & 63, wave = t >> 6;

  // staging: row = j*32 + t/8, source slot = (t&7)^(row&7) (rule 21 inverse-swizzle)
  const unsigned short* aSrc[4];
  const unsigned short* b1Src[4];
  const unsigned short* b3Src[4];
  const unsigned short* w1e = wstage + (size_t)el * 2 * FH;
  const unsigned short* w3e = w1e + FH;
  #pragma unroll
  for (int j = 0; j < 4; ++j) {
    int row = j * 32 + (t >> 3);
    int sl  = (t & 7) ^ (row & 7);
    int mg  = m0 + row;
    int tok = (mg < n_e) ? token_list[off + mg] : 0;
    aSrc[j]  = xbf + (size_t)tok * H_DIM + sl * 8;
    b1Src[j] = w1e + (size_t)(n0 + row) * H_DIM + sl * 8;
    b3Src[j] = w3e + (size_t)(n0 + row) * H_DIM + sl * 8;
  }

  const int lo = lane & 15, hi = lane >> 4;
  const int wm = (wave >> 1) * 64, wn = (wave & 1) * 64;
  const int rbaseA = (wm + lo) * 128;
  const int rbaseB = (wn + lo) * 128;
  const int x0 = ((hi    ) ^ (lo & 7)) << 4;
  const int x1 = ((hi + 4) ^ (lo & 7)) << 4;

  f32x4 accg[4][4], accu[4][4];
  const f32x4 zero = {0.f, 0.f, 0.f, 0.f};
  #pragma unroll
  for (int m = 0; m < 4; ++m)
    #pragma unroll
    for (int n = 0; n < 4; ++n) { accg[m][n] = zero; accu[m][n] = zero; }

  for (int k0 = 0; k0 < H_DIM; k0 += BK) {
    #pragma unroll
    for (int j = 0; j < 4; ++j) {
      gload_lds16(aSrc[j]  + k0, ldsA  + j * 4096 + wave * 1024);
      gload_lds16(b1Src[j] + k0, ldsB1 + j * 4096 + wave * 1024);
      gload_lds16(b3Src[j] + k0, ldsB3 + j * 4096 + wave * 1024);
    }
    __syncthreads();
    #pragma unroll
    for (int kk = 0; kk < 2; ++kk) {
      const int xk = kk ? x1 : x0;
      bf16x8 af[4];
      #pragma unroll
      for (int m = 0; m < 4; ++m)
        af[m] = *(const bf16x8*)(ldsA + rbaseA + m * 2048 + xk);
      #pragma unroll
      for (int n = 0; n < 4; ++n) {
        bf16x8 b1 = *(const bf16x8*)(ldsB1 + rbaseB + n * 2048 + xk);
        bf16x8 b3 = *(const bf16x8*)(ldsB3 + rbaseB + n * 2048 + xk);
        #pragma unroll
        for (int m = 0; m < 4; ++m) {
          accg[m][n] = __builtin_amdgcn_mfma_f32_16x16x32_bf16(af[m], b1, accg[m][n], 0, 0, 0);
          accu[m][n] = __builtin_amdgcn_mfma_f32_16x16x32_bf16(af[m], b3, accu[m][n], 0, 0, 0);
        }
      }
    }
    __syncthreads();
  }
  // epilogue: D row=(lane>>4)*4+r, col=lane&15 (m89/m91 layout)
  #pragma unroll
  for (int m = 0; m < 4; ++m) {
    #pragma unroll
    for (int r = 0; r < 4; ++r) {
      int mg = m0 + wm + m * 16 + hi * 4 + r;
      if (mg < n_e) {
        unsigned short* dst = hbuf + (size_t)(off + mg) * F_DIM + n0 + wn + lo;
        #pragma unroll
        for (int n = 0; n < 4; ++n) {
          float g = accg[m][n][r];
          float u = accu[m][n][r];
          float h = (g / (1.f + expf(-g))) * u;
          dst[n * 16] = f2bf(h);
        }
      }
    }
  }
}

// ---------------- grouped GEMM2: out[tok] += (h w2^T) * slot_w ----------------
// weights from wstage [el][H][F] bf16 for experts e_base..e_base+3
// epilogue: unsafeAtomicAdd into out (exactly 2 contributions/element ->
// commutative fp32 add, bitwise-deterministic; out zeroed beforehand)
__global__ __launch_bounds__(256) void k_gemm2(
    const unsigned short* __restrict__ hbuf, const unsigned short* __restrict__ wstage,
    const int* __restrict__ offsets, const int* __restrict__ token_list,
    const float* __restrict__ slot_w, float* __restrict__ out, int e_base)
{
  const int el  = blockIdx.z;
  const int e   = e_base + el;
  const int off = offsets[e];
  const int n_e = offsets[e + 1] - off;
  const int m0  = blockIdx.y * 128;
  if (m0 >= n_e) return;
  const int n0  = blockIdx.x * 128;

  __shared__ alignas(16) char lds[32768];  // A(16K) | B(16K)
  char* ldsA = lds;
  char* ldsB = lds + 16384;

  const int t = threadIdx.x, lane = t & 63, wave = t >> 6;

  const unsigned short* aSrc[4];
  const unsigned short* bSrc[4];
  const unsigned short* w2e = wstage + (size_t)el * FH;
  #pragma unroll
  for (int j = 0; j < 4; ++j) {
    int row = j * 32 + (t >> 3);
    int sl  = (t & 7) ^ (row & 7);
    int mg  = m0 + row; if (mg >= n_e) mg = n_e - 1;   // clamp: stay in valid hbuf rows
    aSrc[j] = hbuf + (size_t)(off + mg) * F_DIM + sl * 8;
    bSrc[j] = w2e + (size_t)(n0 + row) * F_DIM + sl * 8;
  }

  const int lo = lane & 15, hi = lane >> 4;
  const int wm = (wave >> 1) * 64, wn = (wave & 1) * 64;
  const int rbaseA = (wm + lo) * 128;
  const int rbaseB = (wn + lo) * 128;
  const int x0 = ((hi    ) ^ (lo & 7)) << 4;
  const int x1 = ((hi + 4) ^ (lo & 7)) << 4;

  f32x4 acc[4][4];
  const f32x4 zero = {0.f, 0.f, 0.f, 0.f};
  #pragma unroll
  for (int m = 0; m < 4; ++m)
    #pragma unroll
    for (int n = 0; n < 4; ++n) acc[m][n] = zero;

  for (int k0 = 0; k0 < F_DIM; k0 += BK) {
    #pragma unroll
    for (int j = 0; j < 4; ++j) {
      gload_lds16(aSrc[j] + k0, ldsA + j * 4096 + wave * 1024);
      gload_lds16(bSrc[j] + k0, ldsB + j * 4096 + wave * 1024);
    }
    __syncthreads();
    #pragma unroll
    for (int kk = 0; kk < 2; ++kk) {
      const int xk = kk ? x1 : x0;
      bf16x8 af[4], bfr[4];
      #pragma unroll
      for (int m = 0; m < 4; ++m) af[m]  = *(const bf16x8*)(ldsA + rbaseA + m * 2048 + xk);
      #pragma unroll
      for (int n = 0; n < 4; ++n) bfr[n] = *(const bf16x8*)(ldsB + rbaseB + n * 2048 + xk);
      #pragma unroll
      for (int m = 0; m < 4; ++m)
        #pragma unroll
        for (int n = 0; n < 4; ++n)
          acc[m][n] = __builtin_amdgcn_mfma_f32_16x16x32_bf16(af[m], bfr[n], acc[m][n], 0, 0, 0);
    }
    __syncthreads();
  }
  #pragma unroll
  for (int m = 0; m < 4; ++m) {
    #pragma unroll
    for (int r = 0; r < 4; ++r) {
      int mg = m0 + wm + m * 16 + hi * 4 + r;
      if (mg < n_e) {
        int slot = off + mg;
        int tok  = token_list[slot];
        float sw = slot_w[slot];
        float* dst = out + (size_t)tok * H_DIM + n0 + wn + lo;
        #pragma unroll
        for (int n = 0; n < 4; ++n)
          unsafeAtomicAdd(&dst[n * 16], acc[m][n][r] * sw);
      }
    }
  }
}

// ---------------- launch ----------------
extern "C" void kernel_launch(void* const* d_in, const int* in_sizes, int n_in,
                              void* d_out, int out_size, void* d_ws, size_t ws_size,
                              hipStream_t stream) {
  (void)in_sizes; (void)n_in; (void)out_size; (void)ws_size;
  const float* x  = (const float*)d_in[0];
  const float* gw = (const float*)d_in[1];
  const float* w1 = (const float*)d_in[2];
  const float* w3 = (const float*)d_in[3];
  const float* w2 = (const float*)d_in[4];
  float* out = (float*)d_out;

  char* ws = (char*)d_ws;
  size_t p = 0;
  auto alloc = [&](size_t bytes) -> char* {
    char* r = ws + p;
    p = (p + bytes + 255) & ~(size_t)255;
    return r;
  };
  int*   counts     = (int*)alloc(NE * 4);
  int*   cursors    = (int*)alloc(NE * 4);
  int*   offsets    = (int*)alloc((NE + 1) * 4);
  int*   eids       = (int*)alloc((size_t)NSLOT * 4);
  float* wts        = (float*)alloc((size_t)NSLOT * 4);
  int*   token_list = (int*)alloc((size_t)NSLOT * 4);
  float* slot_w     = (float*)alloc((size_t)NSLOT * 4);
  unsigned short* xbf    = (unsigned short*)alloc((size_t)T_TOK * H_DIM * 2);   // 33.5 MB
  unsigned short* hbuf   = (unsigned short*)alloc((size_t)NSLOT * F_DIM * 2);   // 134.2 MB
  unsigned short* wstage = (unsigned short*)alloc((size_t)EPERPH * 2 * FH * 2); // 134.2 MB
  // total ws ≈ 302.3 MB == round-2-proven footprint

  k_zero<<<dim3(1), dim3(64), 0, stream>>>(counts);
  k_zero_out<<<dim3(2048), dim3(256), 0, stream>>>(out, T_TOK * H_DIM / 4);
  k_cast<<<dim3(2048), dim3(256), 0, stream>>>(x, xbf, T_TOK * H_DIM / 4);
  k_router<<<dim3(T_TOK / 4), dim3(256), 0, stream>>>(x, gw, counts, eids, wts);
  k_prefix<<<dim3(1), dim3(1), 0, stream>>>(counts, offsets, cursors);
  k_scatter<<<dim3(T_TOK / 256), dim3(256), 0, stream>>>(eids, wts, cursors, token_list,
                                                         slot_w);
  // GEMM1 in two phases of 4 experts (wstage reused; stream order serializes)
  for (int eb = 0; eb < NE; eb += EPERPH) {
    k_cast_w13<<<dim3(2048), dim3(256), 0, stream>>>(w1, w3, wstage, eb);
    // worst case 8192 rows/expert -> 64 M-tiles; inactive tiles exit on offsets read
    k_gemm1<<<dim3(F_DIM / 128, 64, EPERPH), dim3(256), 0, stream>>>(
        xbf, wstage, offsets, token_list, hbuf, eb);
  }
  // GEMM2 in two phases of 4 experts; w2 rows for 4 experts are contiguous in src
  for (int eb = 0; eb < NE; eb += EPERPH) {
    k_cast<<<dim3(2048), dim3(256), 0, stream>>>(
        w2 + (size_t)eb * FH, wstage, EPERPH * FH / 4);
    k_gemm2<<<dim3(H_DIM / 128, 64, EPERPH), dim3(256), 0, stream>>>(
        hbuf, wstage, offsets, token_list, slot_w, out, eb);
  }
}